// Round 7
// baseline (2987.301 us; speedup 1.0000x reference)
//
#include <hip/hip_runtime.h>
#include <hip/hip_fp16.h>

#define N_NODES 50000
#define N_EDGES 800000
#define CH 128
#define OUT_CH 64
#define K_ORD 25
#define SLICE ((size_t)N_NODES * CH)   // elements per T_k slice
#define RANGES 4
#define RSZ 12500                      // nodes per source range
#define NODES_PB 49                    // nodes per prop block
#define N4 (N_NODES * RANGES)

typedef __attribute__((ext_vector_type(8))) short s16x8;
typedef __attribute__((ext_vector_type(4))) float f32x4;

union U4H8 { uint4 u; __half2 h2[4]; ushort us[8]; };

// ---------- CSR build: deg (out-degree) + indeg4 (in-degree per src-range) ----------
__global__ void count_kernel(const int* __restrict__ ei, int* __restrict__ deg_i,
                             int* __restrict__ indeg4, int E) {
    int e = blockIdx.x * blockDim.x + threadIdx.x;
    if (e >= E) return;
    int s = ei[e];
    int d = ei[E + e];
    atomicAdd(&deg_i[s], 1);
    atomicAdd(&indeg4[d * RANGES + (s / RSZ)], 1);
}

__global__ __launch_bounds__(256) void scan1_kernel(const int* __restrict__ indeg,
                                                    int* __restrict__ loc,
                                                    int* __restrict__ bsum, int n) {
    __shared__ int tmp[256];
    int tid = threadIdx.x;
    int i = blockIdx.x * 256 + tid;
    int v = (i < n) ? indeg[i] : 0;
    tmp[tid] = v;
    __syncthreads();
    for (int off = 1; off < 256; off <<= 1) {
        int t = (tid >= off) ? tmp[tid - off] : 0;
        __syncthreads();
        tmp[tid] += t;
        __syncthreads();
    }
    if (i < n) loc[i] = tmp[tid] - v;
    if (tid == 255) bsum[blockIdx.x] = tmp[255];
}

__global__ __launch_bounds__(1024) void scan2_kernel(int* __restrict__ bsum, int nb) {
    __shared__ int tmp[1024];
    int tid = threadIdx.x;
    int v = (tid < nb) ? bsum[tid] : 0;
    tmp[tid] = v;
    __syncthreads();
    for (int off = 1; off < 1024; off <<= 1) {
        int t = (tid >= off) ? tmp[tid - off] : 0;
        __syncthreads();
        tmp[tid] += t;
        __syncthreads();
    }
    if (tid < nb) bsum[tid] = tmp[tid] - v;
    if (tid == 1023) bsum[nb] = tmp[1023];
}

__global__ __launch_bounds__(256) void scan3_kernel(const int* __restrict__ loc,
                                                    const int* __restrict__ bsum,
                                                    int* __restrict__ rowptr,
                                                    int* __restrict__ cursor, int n) {
    int i = blockIdx.x * 256 + threadIdx.x;
    if (i < n) {
        int r = loc[i] + bsum[i >> 8];
        rowptr[i] = r;
        cursor[i] = r;
    }
    if (i == n) rowptr[n] = bsum[(n + 255) >> 8];
}

__global__ void scatter_kernel(const int* __restrict__ ei, int* __restrict__ cursor,
                               int* __restrict__ col, int E) {
    int e = blockIdx.x * blockDim.x + threadIdx.x;
    if (e >= E) return;
    int s = ei[e];
    int d = ei[E + e];
    int r = s / RSZ;
    int pos = atomicAdd(&cursor[d * RANGES + r], 1);
    col[pos] = s;
}

// ---------- per-node scale vectors from out-degree ----------
__global__ __launch_bounds__(256) void scaleprep_kernel(const int* __restrict__ deg_i,
                                                        float* __restrict__ beta,
                                                        float* __restrict__ alpha,
                                                        float* __restrict__ gam, int n) {
    int i = blockIdx.x * 256 + threadIdx.x;
    if (i >= n) return;
    int dg = deg_i[i];
    if (dg > 0) {
        float fd = (float)dg;
        beta[i] = -2.f / fd;
        alpha[i] = rsqrtf(fd);
        gam[i] = sqrtf(fd);
    } else {
        beta[i] = 0.f;
        alpha[i] = 1.f;
        gam[i] = 1.f;
    }
}

// ---------- x -> yhat_0 = alpha * x (fp16) ----------
__global__ __launch_bounds__(256) void cvt_kernel(const float* __restrict__ in,
                                                  const float* __restrict__ alpha,
                                                  ushort* __restrict__ out, int n8) {
    int i = blockIdx.x * 256 + threadIdx.x;
    if (i >= n8) return;
    int row = i >> 4;
    float al = alpha[row];
    float4 a = ((const float4*)in)[2 * i];
    float4 b = ((const float4*)in)[2 * i + 1];
    U4H8 p;
    p.h2[0] = __float22half2_rn(make_float2(al * a.x, al * a.y));
    p.h2[1] = __float22half2_rn(make_float2(al * a.z, al * a.w));
    p.h2[2] = __float22half2_rn(make_float2(al * b.x, al * b.y));
    p.h2[3] = __float22half2_rn(make_float2(al * b.z, al * b.w));
    ((uint4*)out)[i] = p.u;
}

// ---------- W prep: WT[k][n][c] = fp16(W[k][c][n]) ----------
__global__ __launch_bounds__(256) void wprep_kernel(const float* __restrict__ W,
                                                    ushort* __restrict__ WT) {
    int idx = blockIdx.x * 256 + threadIdx.x;   // (k, n, c4)
    if (idx >= K_ORD * 128 * 32) return;
    int c4 = idx & 31;
    int nrow = (idx >> 5) & 127;
    int k = idx >> 12;
    const float* Wk = W + (size_t)k * CH * CH;
    ushort o[4];
    #pragma unroll
    for (int j = 0; j < 4; ++j)
        o[j] = __half_as_ushort(__float2half_rn(Wk[(c4 * 4 + j) * CH + nrow]));
    *(ushort2*)(WT + (size_t)k * CH * CH + nrow * CH + c4 * 4)     = make_ushort2(o[0], o[1]);
    *(ushort2*)(WT + (size_t)k * CH * CH + nrow * CH + c4 * 4 + 2) = make_ushort2(o[2], o[3]);
}

// ---------- prop in yhat-space with source-range phasing ----------
// yhat_k[i] = (mode ? beta[i]*G[i] - yprev[i] : 0.5*beta[i]*G[i]),
// G[i] = sum over in-edges of yhat_{k-1}[src]  (unweighted gather).
// Block owns NODES_PB nodes; LDS fp32 acc; ranges processed in order for L2 phasing.
__global__ __launch_bounds__(256) void prop_kernel(
    const ushort* __restrict__ tin, const ushort* __restrict__ tprev,
    ushort* __restrict__ tout, const int* __restrict__ rowptr4,
    const int* __restrict__ col, const float* __restrict__ beta,
    int n, int mode) {
    __shared__ float accs[NODES_PB * 128];
    int tid = threadIdx.x;
    for (int i = tid; i < NODES_PB * 128; i += 256) accs[i] = 0.f;
    __syncthreads();
    int wv = tid >> 6, lane = tid & 63;
    int g = lane >> 4, sub = lane & 15;
    int nbase = blockIdx.x * NODES_PB;

    for (int r = 0; r < RANGES; ++r) {
        for (int ln = wv; ln < NODES_PB; ln += 4) {
            int nid = nbase + ln;
            if (nid >= n) break;
            int beg = rowptr4[nid * RANGES + r];
            int end = rowptr4[nid * RANGES + r + 1];  // contiguous across (node,range)
            if (beg == end) continue;
            float acc[8] = {0.f, 0.f, 0.f, 0.f, 0.f, 0.f, 0.f, 0.f};
            for (int e0 = beg; e0 < end; e0 += 64) {
                int ne = min(64, end - e0);
                int c = 0;
                if (lane < ne) c = col[e0 + lane];
                for (int j4 = 0; j4 < ne; j4 += 4) {
                    int j = j4 + g;
                    int cj = __shfl(c, j & 63);
                    float m = (j < ne) ? 1.f : 0.f;
                    U4H8 v;
                    v.u = ((const uint4*)(tin + (size_t)cj * CH))[sub];
                    #pragma unroll
                    for (int t = 0; t < 4; ++t) {
                        float2 f = __half22float2(v.h2[t]);
                        acc[2 * t]     = fmaf(m, f.x, acc[2 * t]);
                        acc[2 * t + 1] = fmaf(m, f.y, acc[2 * t + 1]);
                    }
                }
            }
            #pragma unroll
            for (int i = 0; i < 8; ++i) {
                acc[i] += __shfl_xor(acc[i], 16);
                acc[i] += __shfl_xor(acc[i], 32);
            }
            if (g == 0) {
                float* row = &accs[ln * 128 + sub * 8];
                #pragma unroll
                for (int i = 0; i < 8; ++i) row[i] += acc[i];
            }
        }
    }
    // finalize: same wave that accumulated writes out (no sync needed)
    for (int ln = wv; ln < NODES_PB; ln += 4) {
        int nid = nbase + ln;
        if (nid >= n) break;
        if (g == 0) {
            float bt = beta[nid];
            const float* row = &accs[ln * 128 + sub * 8];
            size_t base = (size_t)nid * CH + sub * 8;
            float rr[8];
            if (mode) {
                U4H8 pv;
                pv.u = *(const uint4*)(tprev + base);
                #pragma unroll
                for (int t = 0; t < 4; ++t) {
                    float2 f = __half22float2(pv.h2[t]);
                    rr[2 * t]     = fmaf(bt, row[2 * t],     -f.x);
                    rr[2 * t + 1] = fmaf(bt, row[2 * t + 1], -f.y);
                }
            } else {
                #pragma unroll
                for (int i = 0; i < 8; ++i) rr[i] = 0.5f * bt * row[i];
            }
            U4H8 p;
            p.h2[0] = __float22half2_rn(make_float2(rr[0], rr[1]));
            p.h2[1] = __float22half2_rn(make_float2(rr[2], rr[3]));
            p.h2[2] = __float22half2_rn(make_float2(rr[4], rr[5]));
            p.h2[3] = __float22half2_rn(make_float2(rr[6], rr[7]));
            *(uint4*)(tout + base) = p.u;
        }
    }
}

// ---------- GEMM: C[M,128] (beta? +=) Σ_ks (gamma ⊙ Yhat[k0+ks]) @ WT[wk0+ks] ----------
__global__ __launch_bounds__(256) void gemm_kernel(
    const ushort* __restrict__ T, size_t kstride, const ushort* __restrict__ WT,
    const float* __restrict__ gam, float* __restrict__ C,
    int M, int wk0, int nk, int betaf) {
    __shared__ ushort As[128 * 128];
    __shared__ ushort Ws[128 * 128];
    int tid = threadIdx.x;
    int row0 = blockIdx.x * 128;
    int wave = tid >> 6, lane = tid & 63;
    int wrow = wave * 32;
    int lr = lane & 15, kg = lane >> 4;

    f32x4 acc[2][8];
    #pragma unroll
    for (int a = 0; a < 2; ++a)
        #pragma unroll
        for (int c = 0; c < 8; ++c)
            acc[a][c] = (f32x4){0.f, 0.f, 0.f, 0.f};

    for (int ks = 0; ks < nk; ++ks) {
        const ushort* Ak = T + (size_t)ks * kstride;
        const ushort* Wk = WT + (size_t)(wk0 + ks) * (CH * CH);
        #pragma unroll
        for (int i = 0; i < 8; ++i) {
            int idx = tid + i * 256;
            int r = idx >> 4, gg = idx & 15;
            int gr = row0 + r;
            U4H8 hv;
            hv.u = make_uint4(0u, 0u, 0u, 0u);
            if (gr < M) {
                hv.u = ((const uint4*)(Ak + (size_t)gr * CH))[gg];
                float gm = gam[gr];
                #pragma unroll
                for (int t = 0; t < 4; ++t) {
                    float2 f = __half22float2(hv.h2[t]);
                    hv.h2[t] = __float22half2_rn(make_float2(gm * f.x, gm * f.y));
                }
            }
            int gs = gg ^ (r & 15);
            *(uint4*)(&As[r * 128 + gs * 8]) = hv.u;
        }
        #pragma unroll
        for (int i = 0; i < 8; ++i) {
            int idx = tid + i * 256;
            int r = idx >> 4, gg = idx & 15;
            uint4 v = ((const uint4*)(Wk + (size_t)r * CH))[gg];
            int gs = gg ^ (r & 15);
            *(uint4*)(&Ws[r * 128 + gs * 8]) = v;
        }
        __syncthreads();

        #pragma unroll
        for (int kc = 0; kc < 4; ++kc) {
            int gbase = kc * 4 + kg;
            int gs = gbase ^ lr;
            s16x8 a0 = *(const s16x8*)(&As[(wrow + lr) * 128 + gs * 8]);
            s16x8 a1 = *(const s16x8*)(&As[(wrow + 16 + lr) * 128 + gs * 8]);
            #pragma unroll
            for (int c = 0; c < 8; ++c) {
                s16x8 bfr = *(const s16x8*)(&Ws[(c * 16 + lr) * 128 + gs * 8]);
                acc[0][c] = __builtin_amdgcn_mfma_f32_16x16x32_f16(a0, bfr, acc[0][c], 0, 0, 0);
                acc[1][c] = __builtin_amdgcn_mfma_f32_16x16x32_f16(a1, bfr, acc[1][c], 0, 0, 0);
            }
        }
        __syncthreads();
    }

    #pragma unroll
    for (int rf = 0; rf < 2; ++rf)
        #pragma unroll
        for (int c = 0; c < 8; ++c)
            #pragma unroll
            for (int j = 0; j < 4; ++j) {
                int gr = row0 + wrow + rf * 16 + kg * 4 + j;
                int gc = c * 16 + lr;
                if (gr < M) {
                    float v = acc[rf][c][j];
                    if (betaf) v += C[(size_t)gr * 128 + gc];
                    C[(size_t)gr * 128 + gc] = v;
                }
            }
}

// ---------- head: MFMA over Wcat = [w_mu | w_ls], fused leaky+bias+normalize ----------
__global__ __launch_bounds__(256) void head_kernel(
    const float* __restrict__ acc_in, const float* __restrict__ b,
    const float* __restrict__ w_mu, const float* __restrict__ b_mu,
    const float* __restrict__ w_ls, const float* __restrict__ b_ls,
    float* __restrict__ out, int M) {
    __shared__ ushort Hs[128 * 128];
    __shared__ ushort Ws[128 * 128];
    __shared__ float s_b[128];
    int tid = threadIdx.x;
    int row0 = blockIdx.x * 128;
    if (tid < 128) s_b[tid] = b[tid];
    __syncthreads();

    #pragma unroll
    for (int i = 0; i < 16; ++i) {
        int idx = tid + i * 256;
        int r = idx >> 5, c4 = idx & 31;
        float4 v = make_float4(0.f, 0.f, 0.f, 0.f);
        int gr = row0 + r;
        if (gr < M) v = ((const float4*)(acc_in + (size_t)gr * CH))[c4];
        float hv[4] = { v.x, v.y, v.z, v.w };
        #pragma unroll
        for (int j = 0; j < 4; ++j) {
            float h = hv[j] + s_b[c4 * 4 + j];
            hv[j] = h > 0.f ? h : 0.01f * h;
        }
        __half2 p0 = __float22half2_rn(make_float2(hv[0], hv[1]));
        __half2 p1 = __float22half2_rn(make_float2(hv[2], hv[3]));
        int gg = c4 >> 1, hh = c4 & 1;
        int gs = gg ^ (r & 15);
        uint2 pk;
        pk.x = *(unsigned int*)&p0;
        pk.y = *(unsigned int*)&p1;
        *(uint2*)(&Hs[r * 128 + gs * 8 + hh * 4]) = pk;
    }
    #pragma unroll
    for (int i = 0; i < 16; ++i) {
        int idx = tid + i * 256;
        int k = idx >> 5, n4 = idx & 31;
        const float* src = (n4 < 16) ? w_mu : w_ls;
        float4 v = ((const float4*)src)[k * 16 + (n4 & 15)];
        int gk = k >> 3, kk = k & 7;
        float vv[4] = { v.x, v.y, v.z, v.w };
        #pragma unroll
        for (int j = 0; j < 4; ++j) {
            int nn = n4 * 4 + j;
            int gs = gk ^ (nn & 15);
            Ws[nn * 128 + gs * 8 + kk] = __half_as_ushort(__float2half_rn(vv[j]));
        }
    }
    __syncthreads();

    int wave = tid >> 6, lane = tid & 63;
    int wrow = wave * 32;
    int lr = lane & 15, kg = lane >> 4;
    f32x4 acc[2][8];
    #pragma unroll
    for (int a = 0; a < 2; ++a)
        #pragma unroll
        for (int c = 0; c < 8; ++c)
            acc[a][c] = (f32x4){0.f, 0.f, 0.f, 0.f};

    #pragma unroll
    for (int kc = 0; kc < 4; ++kc) {
        int gbase = kc * 4 + kg;
        int gs = gbase ^ lr;
        s16x8 a0 = *(const s16x8*)(&Hs[(wrow + lr) * 128 + gs * 8]);
        s16x8 a1 = *(const s16x8*)(&Hs[(wrow + 16 + lr) * 128 + gs * 8]);
        #pragma unroll
        for (int c = 0; c < 8; ++c) {
            s16x8 bfr = *(const s16x8*)(&Ws[(c * 16 + lr) * 128 + gs * 8]);
            acc[0][c] = __builtin_amdgcn_mfma_f32_16x16x32_f16(a0, bfr, acc[0][c], 0, 0, 0);
            acc[1][c] = __builtin_amdgcn_mfma_f32_16x16x32_f16(a1, bfr, acc[1][c], 0, 0, 0);
        }
    }

    #pragma unroll
    for (int rf = 0; rf < 2; ++rf)
        #pragma unroll
        for (int j = 0; j < 4; ++j) {
            int gr = row0 + wrow + rf * 16 + kg * 4 + j;
            float muv[4], lsv[4];
            float s2 = 0.f;
            #pragma unroll
            for (int c = 0; c < 4; ++c) {
                muv[c] = acc[rf][c][j] + b_mu[c * 16 + lr];
                float l = acc[rf][4 + c][j] + b_ls[c * 16 + lr];
                lsv[c] = l;
                s2 = fmaf(l, l, s2);
            }
            s2 += __shfl_xor(s2, 1);
            s2 += __shfl_xor(s2, 2);
            s2 += __shfl_xor(s2, 4);
            s2 += __shfl_xor(s2, 8);
            float sc = 1.8f / fmaxf(sqrtf(s2), 1e-12f);
            if (gr < M) {
                size_t base = (size_t)gr * OUT_CH;
                #pragma unroll
                for (int c = 0; c < 4; ++c) {
                    int gc = c * 16 + lr;
                    out[base + gc] = muv[c];
                    out[(size_t)N_NODES * OUT_CH + base + gc] = lsv[c] * sc;
                    out[2 * (size_t)N_NODES * OUT_CH + base + gc] = muv[c];
                }
            }
        }
}

// ---------- host ----------
extern "C" void kernel_launch(void* const* d_in, const int* in_sizes, int n_in,
                              void* d_out, int out_size, void* d_ws, size_t ws_size,
                              hipStream_t stream) {
    const float* x    = (const float*)d_in[0];
    const int*   ei   = (const int*)d_in[1];
    const float* W    = (const float*)d_in[2];
    const float* b    = (const float*)d_in[3];
    const float* w_mu = (const float*)d_in[4];
    const float* b_mu = (const float*)d_in[5];
    const float* w_ls = (const float*)d_in[6];
    const float* b_ls = (const float*)d_in[7];

    const int N = N_NODES, E = N_EDGES;
    const int NB4 = (N4 + 255) / 256;          // 782 scan blocks over 200k bins
    char* p = (char*)d_ws;
    auto alloc = [&](size_t bytes) {
        char* r = p;
        p += (bytes + 511) & ~(size_t)511;
        return r;
    };
    int*    deg_i   = (int*)alloc((size_t)N * 4);
    int*    indeg4  = (int*)alloc((size_t)N4 * 4);
    int*    rowptr4 = (int*)alloc((size_t)(N4 + 1) * 4);
    int*    cursor4 = (int*)alloc((size_t)N4 * 4);
    int*    loc     = (int*)alloc((size_t)N4 * 4);
    int*    bsum    = (int*)alloc((size_t)(NB4 + 1) * 4);
    int*    col     = (int*)alloc((size_t)E * 4);
    float*  beta    = (float*)alloc((size_t)N * 4);
    float*  alpha   = (float*)alloc((size_t)N * 4);
    float*  gam     = (float*)alloc((size_t)N * 4);
    ushort* WT      = (ushort*)alloc((size_t)K_ORD * CH * CH * 2);
    float*  accbuf  = (float*)alloc((size_t)N * CH * 4);

    size_t used = (size_t)(p - (char*)d_ws);
    bool bigpath = ws_size >= used + (size_t)K_ORD * SLICE * 2 + (1u << 20);

    hipMemsetAsync(deg_i, 0, (size_t)N * 4, stream);
    hipMemsetAsync(indeg4, 0, (size_t)N4 * 4, stream);

    count_kernel<<<(E + 255) / 256, 256, 0, stream>>>(ei, deg_i, indeg4, E);
    scan1_kernel<<<NB4, 256, 0, stream>>>(indeg4, loc, bsum, N4);
    scan2_kernel<<<1, 1024, 0, stream>>>(bsum, NB4);
    scan3_kernel<<<(N4 + 256) / 256, 256, 0, stream>>>(loc, bsum, rowptr4, cursor4, N4);
    scatter_kernel<<<(E + 255) / 256, 256, 0, stream>>>(ei, cursor4, col, E);
    scaleprep_kernel<<<(N + 255) / 256, 256, 0, stream>>>(deg_i, beta, alpha, gam, N);
    wprep_kernel<<<(K_ORD * 128 * 32 + 255) / 256, 256, 0, stream>>>(W, WT);

    int gemm_grid = (N + 127) / 128;
    int prop_grid = (N + NODES_PB - 1) / NODES_PB;   // 1021 blocks
    int cvt_grid = (N * 16 + 255) / 256;

    if (bigpath) {
        ushort* T = (ushort*)alloc((size_t)K_ORD * SLICE * 2);  // yhat slices fp16
        // yhat_0 = alpha * x
        cvt_kernel<<<cvt_grid, 256, 0, stream>>>(x, alpha, T, N * 16);
        // yhat_1 = 0.5*beta*G(yhat_0)
        prop_kernel<<<prop_grid, 256, 0, stream>>>(T, T, T + SLICE,
                                                   rowptr4, col, beta, N, 0);
        // yhat_k = beta*G(yhat_{k-1}) - yhat_{k-2}
        for (int k = 2; k < K_ORD; ++k)
            prop_kernel<<<prop_grid, 256, 0, stream>>>(
                T + (size_t)(k - 1) * SLICE, T + (size_t)(k - 2) * SLICE,
                T + (size_t)k * SLICE, rowptr4, col, beta, N, 1);
        // acc = sum_k (gamma ⊙ yhat_k) @ W_k  (single K=3200 GEMM)
        gemm_kernel<<<gemm_grid, 256, 0, stream>>>(T, SLICE, WT, gam, accbuf,
                                                   N, 0, K_ORD, 0);
    } else {
        ushort* r0 = (ushort*)alloc(SLICE * 2);
        ushort* r1 = (ushort*)alloc(SLICE * 2);
        ushort* r2 = (ushort*)alloc(SLICE * 2);
        ushort* Ss[3] = { r0, r1, r2 };
        cvt_kernel<<<cvt_grid, 256, 0, stream>>>(x, alpha, r0, N * 16);
        gemm_kernel<<<gemm_grid, 256, 0, stream>>>(r0, 0, WT, gam, accbuf, N, 0, 1, 0);
        prop_kernel<<<prop_grid, 256, 0, stream>>>(r0, r0, r1, rowptr4, col, beta, N, 0);
        gemm_kernel<<<gemm_grid, 256, 0, stream>>>(r1, 0, WT, gam, accbuf, N, 1, 1, 1);
        for (int k = 2; k < K_ORD; ++k) {
            prop_kernel<<<prop_grid, 256, 0, stream>>>(
                Ss[(k - 1) % 3], Ss[(k - 2) % 3], Ss[k % 3], rowptr4, col, beta, N, 1);
            gemm_kernel<<<gemm_grid, 256, 0, stream>>>(Ss[k % 3], 0, WT, gam, accbuf,
                                                       N, k, 1, 1);
        }
    }

    head_kernel<<<gemm_grid, 256, 0, stream>>>(accbuf, b, w_mu, b_mu, w_ls, b_ls,
                                               (float*)d_out, N);
}

// Round 8
// 1503.374 us; speedup vs baseline: 1.9871x; 1.9871x over previous
//
#include <hip/hip_runtime.h>
#include <hip/hip_fp16.h>

#define N_NODES 50000
#define N_EDGES 800000
#define CH 128
#define OUT_CH 64
#define K_ORD 25
#define SLICE ((size_t)N_NODES * CH)   // elements per T_k slice

typedef __attribute__((ext_vector_type(8))) short s16x8;
typedef __attribute__((ext_vector_type(4))) float f32x4;

union U4H8 { uint4 u; __half2 h2[4]; ushort us[8]; };

// ---------- CSR build ----------
__global__ void count_kernel(const int* __restrict__ ei, float* __restrict__ deg,
                             int* __restrict__ indeg, int E) {
    int e = blockIdx.x * blockDim.x + threadIdx.x;
    if (e >= E) return;
    int s = ei[e];
    int d = ei[E + e];
    atomicAdd(&deg[s], 1.0f);
    atomicAdd(&indeg[d], 1);
}

__global__ __launch_bounds__(256) void scan1_kernel(const int* __restrict__ indeg,
                                                    int* __restrict__ loc,
                                                    int* __restrict__ bsum, int n) {
    __shared__ int tmp[256];
    int tid = threadIdx.x;
    int i = blockIdx.x * 256 + tid;
    int v = (i < n) ? indeg[i] : 0;
    tmp[tid] = v;
    __syncthreads();
    for (int off = 1; off < 256; off <<= 1) {
        int t = (tid >= off) ? tmp[tid - off] : 0;
        __syncthreads();
        tmp[tid] += t;
        __syncthreads();
    }
    if (i < n) loc[i] = tmp[tid] - v;
    if (tid == 255) bsum[blockIdx.x] = tmp[255];
}

__global__ __launch_bounds__(256) void scan2_kernel(int* __restrict__ bsum, int nb) {
    __shared__ int tmp[256];
    int tid = threadIdx.x;
    int v = (tid < nb) ? bsum[tid] : 0;
    tmp[tid] = v;
    __syncthreads();
    for (int off = 1; off < 256; off <<= 1) {
        int t = (tid >= off) ? tmp[tid - off] : 0;
        __syncthreads();
        tmp[tid] += t;
        __syncthreads();
    }
    if (tid < nb) bsum[tid] = tmp[tid] - v;
    if (tid == 255) bsum[nb] = tmp[255];
}

__global__ __launch_bounds__(256) void scan3_kernel(const int* __restrict__ loc,
                                                    const int* __restrict__ bsum,
                                                    int* __restrict__ rowptr,
                                                    int* __restrict__ cursor, int n, int nb) {
    int i = blockIdx.x * 256 + threadIdx.x;
    if (i < n) {
        int r = loc[i] + bsum[i >> 8];
        rowptr[i] = r;
        cursor[i] = r;
    }
    if (i == n) rowptr[n] = bsum[nb];
}

__global__ void scatter_kernel(const int* __restrict__ ei, const float* __restrict__ deg,
                               int* __restrict__ cursor, int* __restrict__ col,
                               float* __restrict__ ew, int E) {
    int e = blockIdx.x * blockDim.x + threadIdx.x;
    if (e >= E) return;
    int s = ei[e];
    int d = ei[E + e];
    float ds = deg[s], dd = deg[d];
    float dis_s = ds > 0.f ? rsqrtf(ds) : 0.f;
    float dis_d = dd > 0.f ? rsqrtf(dd) : 0.f;
    int pos = atomicAdd(&cursor[d], 1);
    col[pos] = s;
    ew[pos] = -dis_s * dis_d;
}

// ---------- fp32 -> fp16 convert (x -> T0) ----------
__global__ __launch_bounds__(256) void cvt_kernel(const float* __restrict__ in,
                                                  ushort* __restrict__ out, int n8) {
    int i = blockIdx.x * 256 + threadIdx.x;
    if (i >= n8) return;
    float4 a = ((const float4*)in)[2 * i];
    float4 b = ((const float4*)in)[2 * i + 1];
    U4H8 p;
    p.h2[0] = __float22half2_rn(make_float2(a.x, a.y));
    p.h2[1] = __float22half2_rn(make_float2(a.z, a.w));
    p.h2[2] = __float22half2_rn(make_float2(b.x, b.y));
    p.h2[3] = __float22half2_rn(make_float2(b.z, b.w));
    ((uint4*)out)[i] = p.u;
}

// ---------- W prep: WT[k][n][c] = fp16(W[k][c][n]) ----------
__global__ __launch_bounds__(256) void wprep_kernel(const float* __restrict__ W,
                                                    ushort* __restrict__ WT) {
    int idx = blockIdx.x * 256 + threadIdx.x;   // (k, n, c4)
    if (idx >= K_ORD * 128 * 32) return;
    int c4 = idx & 31;
    int nrow = (idx >> 5) & 127;
    int k = idx >> 12;
    const float* Wk = W + (size_t)k * CH * CH;
    ushort o[4];
    #pragma unroll
    for (int j = 0; j < 4; ++j)
        o[j] = __half_as_ushort(__float2half_rn(Wk[(c4 * 4 + j) * CH + nrow]));
    *(ushort2*)(WT + (size_t)k * CH * CH + nrow * CH + c4 * 4)     = make_ushort2(o[0], o[1]);
    *(ushort2*)(WT + (size_t)k * CH * CH + nrow * CH + c4 * 4 + 2) = make_ushort2(o[2], o[3]);
}

// ---------- prop: tout = (mode ? 2*prop(tin) - tprev : prop(tin)), all fp16 ----------
// one wave per node; 4 groups x 16 lanes; 16-edge unrolled blocks -> MLP=4 per lane
__global__ __launch_bounds__(256) void prop_kernel(
    const ushort* __restrict__ tin, const ushort* __restrict__ tprev,
    ushort* __restrict__ tout, const int* __restrict__ rowptr,
    const int* __restrict__ col, const float* __restrict__ ew, int n, int mode) {
    int wid = blockIdx.x * 4 + (threadIdx.x >> 6);
    if (wid >= n) return;
    int lane = threadIdx.x & 63;
    int g = lane >> 4, sub = lane & 15;
    int beg = rowptr[wid], end = rowptr[wid + 1];
    float acc[8] = {0.f, 0.f, 0.f, 0.f, 0.f, 0.f, 0.f, 0.f};
    for (int e0 = beg; e0 < end; e0 += 64) {
        int ne = min(64, end - e0);
        int c = 0; float w = 0.f;
        if (lane < ne) { c = col[e0 + lane]; w = ew[e0 + lane]; }
        for (int j16 = 0; j16 < ne; j16 += 16) {
            // issue 4 independent gathers (one per unrolled sub-iter) before any FMA
            U4H8 v[4];
            float wj[4];
            #pragma unroll
            for (int u = 0; u < 4; ++u) {
                int j = j16 + u * 4 + g;
                int cj = __shfl(c, j & 63);
                float wf = __shfl(w, j & 63);
                wj[u] = (j < ne) ? wf : 0.f;
                v[u].u = ((const uint4*)(tin + (size_t)cj * CH))[sub];
            }
            #pragma unroll
            for (int u = 0; u < 4; ++u) {
                #pragma unroll
                for (int t = 0; t < 4; ++t) {
                    float2 f = __half22float2(v[u].h2[t]);
                    acc[2 * t]     = fmaf(wj[u], f.x, acc[2 * t]);
                    acc[2 * t + 1] = fmaf(wj[u], f.y, acc[2 * t + 1]);
                }
            }
        }
    }
    #pragma unroll
    for (int i = 0; i < 8; ++i) {
        acc[i] += __shfl_xor(acc[i], 16);
        acc[i] += __shfl_xor(acc[i], 32);
    }
    if (g == 0) {
        size_t base = (size_t)wid * CH + sub * 8;
        float r[8];
        if (mode) {
            U4H8 pv;
            pv.u = *(const uint4*)(tprev + base);
            #pragma unroll
            for (int t = 0; t < 4; ++t) {
                float2 f = __half22float2(pv.h2[t]);
                r[2 * t]     = 2.f * acc[2 * t]     - f.x;
                r[2 * t + 1] = 2.f * acc[2 * t + 1] - f.y;
            }
        } else {
            #pragma unroll
            for (int i = 0; i < 8; ++i) r[i] = acc[i];
        }
        U4H8 p;
        p.h2[0] = __float22half2_rn(make_float2(r[0], r[1]));
        p.h2[1] = __float22half2_rn(make_float2(r[2], r[3]));
        p.h2[2] = __float22half2_rn(make_float2(r[4], r[5]));
        p.h2[3] = __float22half2_rn(make_float2(r[6], r[7]));
        *(uint4*)(tout + base) = p.u;
    }
}

// ---------- GEMM: C[M,128] (beta? +=) Σ_{ks} T[k0+ks] @ W[k0+ks], fp16 MFMA ----------
__global__ __launch_bounds__(256) void gemm_kernel(
    const ushort* __restrict__ T, size_t slice_stride, const ushort* __restrict__ WT,
    float* __restrict__ C, int M, int k0, int nk, int beta) {
    __shared__ ushort As[128 * 128];
    __shared__ ushort Ws[128 * 128];
    int tid = threadIdx.x;
    int row0 = blockIdx.x * 128;
    int wave = tid >> 6, lane = tid & 63;
    int wrow = wave * 32;
    int lr = lane & 15, kg = lane >> 4;

    f32x4 acc[2][8];
    #pragma unroll
    for (int a = 0; a < 2; ++a)
        #pragma unroll
        for (int c = 0; c < 8; ++c)
            acc[a][c] = (f32x4){0.f, 0.f, 0.f, 0.f};

    for (int ks = 0; ks < nk; ++ks) {
        const ushort* Ak = T + (size_t)(k0 + ks) * slice_stride;
        const ushort* Wk = WT + (size_t)(k0 + ks) * (CH * CH);
        #pragma unroll
        for (int i = 0; i < 8; ++i) {
            int idx = tid + i * 256;
            int r = idx >> 4, gg = idx & 15;
            uint4 v = make_uint4(0u, 0u, 0u, 0u);
            int gr = row0 + r;
            if (gr < M) v = ((const uint4*)(Ak + (size_t)gr * CH))[gg];
            int gs = gg ^ (r & 15);
            *(uint4*)(&As[r * 128 + gs * 8]) = v;
        }
        #pragma unroll
        for (int i = 0; i < 8; ++i) {
            int idx = tid + i * 256;
            int r = idx >> 4, gg = idx & 15;
            uint4 v = ((const uint4*)(Wk + (size_t)r * CH))[gg];
            int gs = gg ^ (r & 15);
            *(uint4*)(&Ws[r * 128 + gs * 8]) = v;
        }
        __syncthreads();

        #pragma unroll
        for (int kc = 0; kc < 4; ++kc) {
            int gbase = kc * 4 + kg;
            int gs = gbase ^ lr;
            s16x8 a0 = *(const s16x8*)(&As[(wrow + lr) * 128 + gs * 8]);
            s16x8 a1 = *(const s16x8*)(&As[(wrow + 16 + lr) * 128 + gs * 8]);
            #pragma unroll
            for (int c = 0; c < 8; ++c) {
                s16x8 bfr = *(const s16x8*)(&Ws[(c * 16 + lr) * 128 + gs * 8]);
                acc[0][c] = __builtin_amdgcn_mfma_f32_16x16x32_f16(a0, bfr, acc[0][c], 0, 0, 0);
                acc[1][c] = __builtin_amdgcn_mfma_f32_16x16x32_f16(a1, bfr, acc[1][c], 0, 0, 0);
            }
        }
        __syncthreads();
    }

    #pragma unroll
    for (int rf = 0; rf < 2; ++rf)
        #pragma unroll
        for (int c = 0; c < 8; ++c)
            #pragma unroll
            for (int j = 0; j < 4; ++j) {
                int gr = row0 + wrow + rf * 16 + kg * 4 + j;
                int gc = c * 16 + lr;
                if (gr < M) {
                    float v = acc[rf][c][j];
                    if (beta) v += C[(size_t)gr * 128 + gc];
                    C[(size_t)gr * 128 + gc] = v;
                }
            }
}

// ---------- head: MFMA over Wcat = [w_mu | w_ls], fused leaky+bias+normalize ----------
__global__ __launch_bounds__(256) void head_kernel(
    const float* __restrict__ acc_in, const float* __restrict__ b,
    const float* __restrict__ w_mu, const float* __restrict__ b_mu,
    const float* __restrict__ w_ls, const float* __restrict__ b_ls,
    float* __restrict__ out, int M) {
    __shared__ ushort Hs[128 * 128];
    __shared__ ushort Ws[128 * 128];
    __shared__ float s_b[128];
    int tid = threadIdx.x;
    int row0 = blockIdx.x * 128;
    if (tid < 128) s_b[tid] = b[tid];
    __syncthreads();

    #pragma unroll
    for (int i = 0; i < 16; ++i) {
        int idx = tid + i * 256;
        int r = idx >> 5, c4 = idx & 31;
        float4 v = make_float4(0.f, 0.f, 0.f, 0.f);
        int gr = row0 + r;
        if (gr < M) v = ((const float4*)(acc_in + (size_t)gr * CH))[c4];
        float hv[4] = { v.x, v.y, v.z, v.w };
        #pragma unroll
        for (int j = 0; j < 4; ++j) {
            float h = hv[j] + s_b[c4 * 4 + j];
            hv[j] = h > 0.f ? h : 0.01f * h;
        }
        __half2 p0 = __float22half2_rn(make_float2(hv[0], hv[1]));
        __half2 p1 = __float22half2_rn(make_float2(hv[2], hv[3]));
        int gg = c4 >> 1, hh = c4 & 1;
        int gs = gg ^ (r & 15);
        uint2 pk;
        pk.x = *(unsigned int*)&p0;
        pk.y = *(unsigned int*)&p1;
        *(uint2*)(&Hs[r * 128 + gs * 8 + hh * 4]) = pk;
    }
    #pragma unroll
    for (int i = 0; i < 16; ++i) {
        int idx = tid + i * 256;
        int k = idx >> 5, n4 = idx & 31;
        const float* src = (n4 < 16) ? w_mu : w_ls;
        float4 v = ((const float4*)src)[k * 16 + (n4 & 15)];
        int gk = k >> 3, kk = k & 7;
        float vv[4] = { v.x, v.y, v.z, v.w };
        #pragma unroll
        for (int j = 0; j < 4; ++j) {
            int nn = n4 * 4 + j;
            int gs = gk ^ (nn & 15);
            Ws[nn * 128 + gs * 8 + kk] = __half_as_ushort(__float2half_rn(vv[j]));
        }
    }
    __syncthreads();

    int wave = tid >> 6, lane = tid & 63;
    int wrow = wave * 32;
    int lr = lane & 15, kg = lane >> 4;
    f32x4 acc[2][8];
    #pragma unroll
    for (int a = 0; a < 2; ++a)
        #pragma unroll
        for (int c = 0; c < 8; ++c)
            acc[a][c] = (f32x4){0.f, 0.f, 0.f, 0.f};

    #pragma unroll
    for (int kc = 0; kc < 4; ++kc) {
        int gbase = kc * 4 + kg;
        int gs = gbase ^ lr;
        s16x8 a0 = *(const s16x8*)(&Hs[(wrow + lr) * 128 + gs * 8]);
        s16x8 a1 = *(const s16x8*)(&Hs[(wrow + 16 + lr) * 128 + gs * 8]);
        #pragma unroll
        for (int c = 0; c < 8; ++c) {
            s16x8 bfr = *(const s16x8*)(&Ws[(c * 16 + lr) * 128 + gs * 8]);
            acc[0][c] = __builtin_amdgcn_mfma_f32_16x16x32_f16(a0, bfr, acc[0][c], 0, 0, 0);
            acc[1][c] = __builtin_amdgcn_mfma_f32_16x16x32_f16(a1, bfr, acc[1][c], 0, 0, 0);
        }
    }

    #pragma unroll
    for (int rf = 0; rf < 2; ++rf)
        #pragma unroll
        for (int j = 0; j < 4; ++j) {
            int gr = row0 + wrow + rf * 16 + kg * 4 + j;
            float muv[4], lsv[4];
            float s2 = 0.f;
            #pragma unroll
            for (int c = 0; c < 4; ++c) {
                muv[c] = acc[rf][c][j] + b_mu[c * 16 + lr];
                float l = acc[rf][4 + c][j] + b_ls[c * 16 + lr];
                lsv[c] = l;
                s2 = fmaf(l, l, s2);
            }
            s2 += __shfl_xor(s2, 1);
            s2 += __shfl_xor(s2, 2);
            s2 += __shfl_xor(s2, 4);
            s2 += __shfl_xor(s2, 8);
            float sc = 1.8f / fmaxf(sqrtf(s2), 1e-12f);
            if (gr < M) {
                size_t base = (size_t)gr * OUT_CH;
                #pragma unroll
                for (int c = 0; c < 4; ++c) {
                    int gc = c * 16 + lr;
                    out[base + gc] = muv[c];
                    out[(size_t)N_NODES * OUT_CH + base + gc] = lsv[c] * sc;
                    out[2 * (size_t)N_NODES * OUT_CH + base + gc] = muv[c];
                }
            }
        }
}

// ---------- host ----------
extern "C" void kernel_launch(void* const* d_in, const int* in_sizes, int n_in,
                              void* d_out, int out_size, void* d_ws, size_t ws_size,
                              hipStream_t stream) {
    const float* x    = (const float*)d_in[0];
    const int*   ei   = (const int*)d_in[1];
    const float* W    = (const float*)d_in[2];
    const float* b    = (const float*)d_in[3];
    const float* w_mu = (const float*)d_in[4];
    const float* b_mu = (const float*)d_in[5];
    const float* w_ls = (const float*)d_in[6];
    const float* b_ls = (const float*)d_in[7];

    const int N = N_NODES, E = N_EDGES;
    const int NB = (N + 255) / 256;
    char* p = (char*)d_ws;
    auto alloc = [&](size_t bytes) {
        char* r = p;
        p += (bytes + 511) & ~(size_t)511;
        return r;
    };
    float*  deg    = (float*)alloc((size_t)N * 4);
    int*    indeg  = (int*)alloc((size_t)N * 4);
    int*    rowptr = (int*)alloc((size_t)(N + 1) * 4);
    int*    cursor = (int*)alloc((size_t)N * 4);
    int*    loc    = (int*)alloc((size_t)N * 4);
    int*    bsum   = (int*)alloc((size_t)(NB + 1) * 4);
    int*    col    = (int*)alloc((size_t)E * 4);
    float*  ew     = (float*)alloc((size_t)E * 4);
    ushort* WT     = (ushort*)alloc((size_t)K_ORD * CH * CH * 2);
    float*  accbuf = (float*)alloc((size_t)N * CH * 4);

    size_t used = (size_t)(p - (char*)d_ws);
    bool bigpath = ws_size >= used + (size_t)K_ORD * SLICE * 2 + (1u << 20);

    hipMemsetAsync(deg, 0, (size_t)N * 4, stream);
    hipMemsetAsync(indeg, 0, (size_t)N * 4, stream);

    count_kernel<<<(E + 255) / 256, 256, 0, stream>>>(ei, deg, indeg, E);
    scan1_kernel<<<NB, 256, 0, stream>>>(indeg, loc, bsum, N);
    scan2_kernel<<<1, 256, 0, stream>>>(bsum, NB);
    scan3_kernel<<<NB, 256, 0, stream>>>(loc, bsum, rowptr, cursor, N, NB);
    scatter_kernel<<<(E + 255) / 256, 256, 0, stream>>>(ei, deg, cursor, col, ew, E);
    wprep_kernel<<<(K_ORD * 128 * 32 + 255) / 256, 256, 0, stream>>>(W, WT);

    int gemm_grid = (N + 127) / 128;
    int prop_grid = (N + 3) / 4;
    int cvt_grid = (N * 16 + 255) / 256;

    if (bigpath) {
        ushort* T = (ushort*)alloc((size_t)K_ORD * SLICE * 2);  // [K][N][128] fp16
        // T0 = fp16(x)
        cvt_kernel<<<cvt_grid, 256, 0, stream>>>(x, T, N * 16);
        // T1 = prop(T0)
        prop_kernel<<<prop_grid, 256, 0, stream>>>(T, T, T + SLICE,
                                                   rowptr, col, ew, N, 0);
        // Tk = 2*prop(T_{k-1}) - T_{k-2}
        for (int k = 2; k < K_ORD; ++k)
            prop_kernel<<<prop_grid, 256, 0, stream>>>(
                T + (size_t)(k - 1) * SLICE, T + (size_t)(k - 2) * SLICE,
                T + (size_t)k * SLICE, rowptr, col, ew, N, 1);
        // acc = sum_k T_k @ W_k  (single K=3200 GEMM)
        gemm_kernel<<<gemm_grid, 256, 0, stream>>>(T, SLICE, WT, accbuf, N, 0, K_ORD, 0);
    } else {
        ushort* r0 = (ushort*)alloc(SLICE * 2);
        ushort* r1 = (ushort*)alloc(SLICE * 2);
        ushort* r2 = (ushort*)alloc(SLICE * 2);
        ushort* Ss[3] = { r0, r1, r2 };
        cvt_kernel<<<cvt_grid, 256, 0, stream>>>(x, r0, N * 16);
        gemm_kernel<<<gemm_grid, 256, 0, stream>>>(r0, 0, WT, accbuf, N, 0, 1, 0);
        prop_kernel<<<prop_grid, 256, 0, stream>>>(r0, r0, r1, rowptr, col, ew, N, 0);
        gemm_kernel<<<gemm_grid, 256, 0, stream>>>(r1, 0, WT, accbuf, N, 1, 1, 1);
        for (int k = 2; k < K_ORD; ++k) {
            prop_kernel<<<prop_grid, 256, 0, stream>>>(
                Ss[(k - 1) % 3], Ss[(k - 2) % 3], Ss[k % 3], rowptr, col, ew, N, 1);
            gemm_kernel<<<gemm_grid, 256, 0, stream>>>(Ss[k % 3], 0, WT, accbuf, N, k, 1, 1);
        }
    }

    head_kernel<<<gemm_grid, 256, 0, stream>>>(accbuf, b, w_mu, b_mu, w_ls, b_ls,
                                               (float*)d_out, N);
}

// Round 9
// 1502.529 us; speedup vs baseline: 1.9882x; 1.0006x over previous
//
#include <hip/hip_runtime.h>
#include <hip/hip_fp16.h>
#include <hip/hip_cooperative_groups.h>

namespace cg = cooperative_groups;

#define N_NODES 50000
#define N_EDGES 800000
#define CH 128
#define OUT_CH 64
#define K_ORD 25
#define SLICE ((size_t)N_NODES * CH)   // elements per T_k slice
#define NPB 49                         // nodes per cooperative block
#define GRID_C 1024                    // 4 blocks/CU x 256 CUs (co-resident)

typedef __attribute__((ext_vector_type(8))) short s16x8;
typedef __attribute__((ext_vector_type(4))) float f32x4;

union U4H8 { uint4 u; __half2 h2[4]; ushort us[8]; };

// ---------- CSR build ----------
__global__ void count_kernel(const int* __restrict__ ei, float* __restrict__ deg,
                             int* __restrict__ indeg, int E) {
    int e = blockIdx.x * blockDim.x + threadIdx.x;
    if (e >= E) return;
    int s = ei[e];
    int d = ei[E + e];
    atomicAdd(&deg[s], 1.0f);
    atomicAdd(&indeg[d], 1);
}

__global__ __launch_bounds__(256) void scan1_kernel(const int* __restrict__ indeg,
                                                    int* __restrict__ loc,
                                                    int* __restrict__ bsum, int n) {
    __shared__ int tmp[256];
    int tid = threadIdx.x;
    int i = blockIdx.x * 256 + tid;
    int v = (i < n) ? indeg[i] : 0;
    tmp[tid] = v;
    __syncthreads();
    for (int off = 1; off < 256; off <<= 1) {
        int t = (tid >= off) ? tmp[tid - off] : 0;
        __syncthreads();
        tmp[tid] += t;
        __syncthreads();
    }
    if (i < n) loc[i] = tmp[tid] - v;
    if (tid == 255) bsum[blockIdx.x] = tmp[255];
}

__global__ __launch_bounds__(256) void scan2_kernel(int* __restrict__ bsum, int nb) {
    __shared__ int tmp[256];
    int tid = threadIdx.x;
    int v = (tid < nb) ? bsum[tid] : 0;
    tmp[tid] = v;
    __syncthreads();
    for (int off = 1; off < 256; off <<= 1) {
        int t = (tid >= off) ? tmp[tid - off] : 0;
        __syncthreads();
        tmp[tid] += t;
        __syncthreads();
    }
    if (tid < nb) bsum[tid] = tmp[tid] - v;
    if (tid == 255) bsum[nb] = tmp[255];
}

__global__ __launch_bounds__(256) void scan3_kernel(const int* __restrict__ loc,
                                                    const int* __restrict__ bsum,
                                                    int* __restrict__ rowptr,
                                                    int* __restrict__ cursor, int n, int nb) {
    int i = blockIdx.x * 256 + threadIdx.x;
    if (i < n) {
        int r = loc[i] + bsum[i >> 8];
        rowptr[i] = r;
        cursor[i] = r;
    }
    if (i == n) rowptr[n] = bsum[nb];
}

__global__ void scatter_kernel(const int* __restrict__ ei, const float* __restrict__ deg,
                               int* __restrict__ cursor, int* __restrict__ col,
                               float* __restrict__ ew, int E) {
    int e = blockIdx.x * blockDim.x + threadIdx.x;
    if (e >= E) return;
    int s = ei[e];
    int d = ei[E + e];
    float ds = deg[s], dd = deg[d];
    float dis_s = ds > 0.f ? rsqrtf(ds) : 0.f;
    float dis_d = dd > 0.f ? rsqrtf(dd) : 0.f;
    int pos = atomicAdd(&cursor[d], 1);
    col[pos] = s;
    ew[pos] = -dis_s * dis_d;
}

// ---------- fp32 -> fp16 convert (x -> T0), smallpath only ----------
__global__ __launch_bounds__(256) void cvt_kernel(const float* __restrict__ in,
                                                  ushort* __restrict__ out, int n8) {
    int i = blockIdx.x * 256 + threadIdx.x;
    if (i >= n8) return;
    float4 a = ((const float4*)in)[2 * i];
    float4 b = ((const float4*)in)[2 * i + 1];
    U4H8 p;
    p.h2[0] = __float22half2_rn(make_float2(a.x, a.y));
    p.h2[1] = __float22half2_rn(make_float2(a.z, a.w));
    p.h2[2] = __float22half2_rn(make_float2(b.x, b.y));
    p.h2[3] = __float22half2_rn(make_float2(b.z, b.w));
    ((uint4*)out)[i] = p.u;
}

// ---------- W prep: WT[k][n][c] = fp16(W[k][c][n]) ----------
__global__ __launch_bounds__(256) void wprep_kernel(const float* __restrict__ W,
                                                    ushort* __restrict__ WT) {
    int idx = blockIdx.x * 256 + threadIdx.x;   // (k, n, c4)
    if (idx >= K_ORD * 128 * 32) return;
    int c4 = idx & 31;
    int nrow = (idx >> 5) & 127;
    int k = idx >> 12;
    const float* Wk = W + (size_t)k * CH * CH;
    ushort o[4];
    #pragma unroll
    for (int j = 0; j < 4; ++j)
        o[j] = __half_as_ushort(__float2half_rn(Wk[(c4 * 4 + j) * CH + nrow]));
    *(ushort2*)(WT + (size_t)k * CH * CH + nrow * CH + c4 * 4)     = make_ushort2(o[0], o[1]);
    *(ushort2*)(WT + (size_t)k * CH * CH + nrow * CH + c4 * 4 + 2) = make_ushort2(o[2], o[3]);
}

// ---------- fused Chebyshev: persistent blocks, tprev in LDS ping-pong ----------
// Each block owns NPB nodes for all K steps. pv[k&1][ln] holds T_k rows of my nodes.
// Step k: gather G from global T_{k-1}; T_k = (k==1 ? G : 2G - pv[k&1]); write pv + global.
__global__ __launch_bounds__(256) void cheb_kernel(
    const float* __restrict__ x, ushort* __restrict__ T,
    const int* __restrict__ rowptr, const int* __restrict__ col,
    const float* __restrict__ ew, int n) {
    cg::grid_group grid = cg::this_grid();
    __shared__ ushort pv[2][NPB][CH];     // 25088 B
    int tid = threadIdx.x;
    int wv = tid >> 6, lane = tid & 63;
    int gq = lane >> 4, sub = lane & 15;
    int nbase = blockIdx.x * NPB;

    // T0 = fp16(x) for my nodes (LDS + global)
    for (int ln = wv; ln < NPB; ln += 4) {
        int nid = nbase + ln;
        if (nid >= n) break;
        float2 f = ((const float2*)(x + (size_t)nid * CH))[lane];
        __half2 h = __float22half2_rn(f);
        unsigned int u = *(unsigned int*)&h;
        *(unsigned int*)&pv[0][ln][lane * 2] = u;
        *(unsigned int*)(T + (size_t)nid * CH + lane * 2) = u;
    }
    grid.sync();

    for (int k = 1; k < K_ORD; ++k) {
        const ushort* tin = T + (size_t)(k - 1) * SLICE;
        ushort* tout = T + (size_t)k * SLICE;
        int pb = k & 1;
        for (int ln = wv; ln < NPB; ln += 4) {
            int nid = nbase + ln;
            if (nid >= n) break;
            int beg = rowptr[nid], end = rowptr[nid + 1];
            float acc[8] = {0.f, 0.f, 0.f, 0.f, 0.f, 0.f, 0.f, 0.f};
            for (int e0 = beg; e0 < end; e0 += 64) {
                int ne = min(64, end - e0);
                int c = 0; float w = 0.f;
                if (lane < ne) { c = col[e0 + lane]; w = ew[e0 + lane]; }
                for (int j16 = 0; j16 < ne; j16 += 16) {
                    U4H8 v[4];
                    float wj[4];
                    #pragma unroll
                    for (int u = 0; u < 4; ++u) {
                        int j = j16 + u * 4 + gq;
                        int cj = __shfl(c, j & 63);
                        float wf = __shfl(w, j & 63);
                        wj[u] = (j < ne) ? wf : 0.f;
                        v[u].u = ((const uint4*)(tin + (size_t)cj * CH))[sub];
                    }
                    #pragma unroll
                    for (int u = 0; u < 4; ++u) {
                        #pragma unroll
                        for (int t = 0; t < 4; ++t) {
                            float2 f = __half22float2(v[u].h2[t]);
                            acc[2 * t]     = fmaf(wj[u], f.x, acc[2 * t]);
                            acc[2 * t + 1] = fmaf(wj[u], f.y, acc[2 * t + 1]);
                        }
                    }
                }
            }
            #pragma unroll
            for (int i = 0; i < 8; ++i) {
                acc[i] += __shfl_xor(acc[i], 16);
                acc[i] += __shfl_xor(acc[i], 32);
            }
            if (gq == 0) {
                float r[8];
                if (k == 1) {
                    #pragma unroll
                    for (int i = 0; i < 8; ++i) r[i] = acc[i];
                } else {
                    U4H8 pvv;
                    pvv.u = *(const uint4*)&pv[pb][ln][sub * 8];
                    #pragma unroll
                    for (int t = 0; t < 4; ++t) {
                        float2 f = __half22float2(pvv.h2[t]);
                        r[2 * t]     = 2.f * acc[2 * t]     - f.x;
                        r[2 * t + 1] = 2.f * acc[2 * t + 1] - f.y;
                    }
                }
                U4H8 p;
                p.h2[0] = __float22half2_rn(make_float2(r[0], r[1]));
                p.h2[1] = __float22half2_rn(make_float2(r[2], r[3]));
                p.h2[2] = __float22half2_rn(make_float2(r[4], r[5]));
                p.h2[3] = __float22half2_rn(make_float2(r[6], r[7]));
                *(uint4*)&pv[pb][ln][sub * 8] = p.u;
                *(uint4*)(tout + (size_t)nid * CH + sub * 8) = p.u;
            }
        }
        grid.sync();
    }
}

// ---------- prop (smallpath fallback) ----------
__global__ __launch_bounds__(256) void prop_kernel(
    const ushort* __restrict__ tin, const ushort* __restrict__ tprev,
    ushort* __restrict__ tout, const int* __restrict__ rowptr,
    const int* __restrict__ col, const float* __restrict__ ew, int n, int mode) {
    int wid = blockIdx.x * 4 + (threadIdx.x >> 6);
    if (wid >= n) return;
    int lane = threadIdx.x & 63;
    int g = lane >> 4, sub = lane & 15;
    int beg = rowptr[wid], end = rowptr[wid + 1];
    float acc[8] = {0.f, 0.f, 0.f, 0.f, 0.f, 0.f, 0.f, 0.f};
    for (int e0 = beg; e0 < end; e0 += 64) {
        int ne = min(64, end - e0);
        int c = 0; float w = 0.f;
        if (lane < ne) { c = col[e0 + lane]; w = ew[e0 + lane]; }
        for (int j16 = 0; j16 < ne; j16 += 16) {
            U4H8 v[4];
            float wj[4];
            #pragma unroll
            for (int u = 0; u < 4; ++u) {
                int j = j16 + u * 4 + g;
                int cj = __shfl(c, j & 63);
                float wf = __shfl(w, j & 63);
                wj[u] = (j < ne) ? wf : 0.f;
                v[u].u = ((const uint4*)(tin + (size_t)cj * CH))[sub];
            }
            #pragma unroll
            for (int u = 0; u < 4; ++u) {
                #pragma unroll
                for (int t = 0; t < 4; ++t) {
                    float2 f = __half22float2(v[u].h2[t]);
                    acc[2 * t]     = fmaf(wj[u], f.x, acc[2 * t]);
                    acc[2 * t + 1] = fmaf(wj[u], f.y, acc[2 * t + 1]);
                }
            }
        }
    }
    #pragma unroll
    for (int i = 0; i < 8; ++i) {
        acc[i] += __shfl_xor(acc[i], 16);
        acc[i] += __shfl_xor(acc[i], 32);
    }
    if (g == 0) {
        size_t base = (size_t)wid * CH + sub * 8;
        float r[8];
        if (mode) {
            U4H8 pv;
            pv.u = *(const uint4*)(tprev + base);
            #pragma unroll
            for (int t = 0; t < 4; ++t) {
                float2 f = __half22float2(pv.h2[t]);
                r[2 * t]     = 2.f * acc[2 * t]     - f.x;
                r[2 * t + 1] = 2.f * acc[2 * t + 1] - f.y;
            }
        } else {
            #pragma unroll
            for (int i = 0; i < 8; ++i) r[i] = acc[i];
        }
        U4H8 p;
        p.h2[0] = __float22half2_rn(make_float2(r[0], r[1]));
        p.h2[1] = __float22half2_rn(make_float2(r[2], r[3]));
        p.h2[2] = __float22half2_rn(make_float2(r[4], r[5]));
        p.h2[3] = __float22half2_rn(make_float2(r[6], r[7]));
        *(uint4*)(tout + base) = p.u;
    }
}

// ---------- GEMM: C[M,128] (beta? +=) Σ_{ks} T[k0+ks] @ W[k0+ks], fp16 MFMA ----------
__global__ __launch_bounds__(256) void gemm_kernel(
    const ushort* __restrict__ T, size_t slice_stride, const ushort* __restrict__ WT,
    float* __restrict__ C, int M, int k0, int nk, int beta) {
    __shared__ ushort As[128 * 128];
    __shared__ ushort Ws[128 * 128];
    int tid = threadIdx.x;
    int row0 = blockIdx.x * 128;
    int wave = tid >> 6, lane = tid & 63;
    int wrow = wave * 32;
    int lr = lane & 15, kg = lane >> 4;

    f32x4 acc[2][8];
    #pragma unroll
    for (int a = 0; a < 2; ++a)
        #pragma unroll
        for (int c = 0; c < 8; ++c)
            acc[a][c] = (f32x4){0.f, 0.f, 0.f, 0.f};

    for (int ks = 0; ks < nk; ++ks) {
        const ushort* Ak = T + (size_t)(k0 + ks) * slice_stride;
        const ushort* Wk = WT + (size_t)(k0 + ks) * (CH * CH);
        #pragma unroll
        for (int i = 0; i < 8; ++i) {
            int idx = tid + i * 256;
            int r = idx >> 4, gg = idx & 15;
            uint4 v = make_uint4(0u, 0u, 0u, 0u);
            int gr = row0 + r;
            if (gr < M) v = ((const uint4*)(Ak + (size_t)gr * CH))[gg];
            int gs = gg ^ (r & 15);
            *(uint4*)(&As[r * 128 + gs * 8]) = v;
        }
        #pragma unroll
        for (int i = 0; i < 8; ++i) {
            int idx = tid + i * 256;
            int r = idx >> 4, gg = idx & 15;
            uint4 v = ((const uint4*)(Wk + (size_t)r * CH))[gg];
            int gs = gg ^ (r & 15);
            *(uint4*)(&Ws[r * 128 + gs * 8]) = v;
        }
        __syncthreads();

        #pragma unroll
        for (int kc = 0; kc < 4; ++kc) {
            int gbase = kc * 4 + kg;
            int gs = gbase ^ lr;
            s16x8 a0 = *(const s16x8*)(&As[(wrow + lr) * 128 + gs * 8]);
            s16x8 a1 = *(const s16x8*)(&As[(wrow + 16 + lr) * 128 + gs * 8]);
            #pragma unroll
            for (int c = 0; c < 8; ++c) {
                s16x8 bfr = *(const s16x8*)(&Ws[(c * 16 + lr) * 128 + gs * 8]);
                acc[0][c] = __builtin_amdgcn_mfma_f32_16x16x32_f16(a0, bfr, acc[0][c], 0, 0, 0);
                acc[1][c] = __builtin_amdgcn_mfma_f32_16x16x32_f16(a1, bfr, acc[1][c], 0, 0, 0);
            }
        }
        __syncthreads();
    }

    #pragma unroll
    for (int rf = 0; rf < 2; ++rf)
        #pragma unroll
        for (int c = 0; c < 8; ++c)
            #pragma unroll
            for (int j = 0; j < 4; ++j) {
                int gr = row0 + wrow + rf * 16 + kg * 4 + j;
                int gc = c * 16 + lr;
                if (gr < M) {
                    float v = acc[rf][c][j];
                    if (beta) v += C[(size_t)gr * 128 + gc];
                    C[(size_t)gr * 128 + gc] = v;
                }
            }
}

// ---------- head: MFMA over Wcat = [w_mu | w_ls], fused leaky+bias+normalize ----------
__global__ __launch_bounds__(256) void head_kernel(
    const float* __restrict__ acc_in, const float* __restrict__ b,
    const float* __restrict__ w_mu, const float* __restrict__ b_mu,
    const float* __restrict__ w_ls, const float* __restrict__ b_ls,
    float* __restrict__ out, int M) {
    __shared__ ushort Hs[128 * 128];
    __shared__ ushort Ws[128 * 128];
    __shared__ float s_b[128];
    int tid = threadIdx.x;
    int row0 = blockIdx.x * 128;
    if (tid < 128) s_b[tid] = b[tid];
    __syncthreads();

    #pragma unroll
    for (int i = 0; i < 16; ++i) {
        int idx = tid + i * 256;
        int r = idx >> 5, c4 = idx & 31;
        float4 v = make_float4(0.f, 0.f, 0.f, 0.f);
        int gr = row0 + r;
        if (gr < M) v = ((const float4*)(acc_in + (size_t)gr * CH))[c4];
        float hv[4] = { v.x, v.y, v.z, v.w };
        #pragma unroll
        for (int j = 0; j < 4; ++j) {
            float h = hv[j] + s_b[c4 * 4 + j];
            hv[j] = h > 0.f ? h : 0.01f * h;
        }
        __half2 p0 = __float22half2_rn(make_float2(hv[0], hv[1]));
        __half2 p1 = __float22half2_rn(make_float2(hv[2], hv[3]));
        int gg = c4 >> 1, hh = c4 & 1;
        int gs = gg ^ (r & 15);
        uint2 pk;
        pk.x = *(unsigned int*)&p0;
        pk.y = *(unsigned int*)&p1;
        *(uint2*)(&Hs[r * 128 + gs * 8 + hh * 4]) = pk;
    }
    #pragma unroll
    for (int i = 0; i < 16; ++i) {
        int idx = tid + i * 256;
        int k = idx >> 5, n4 = idx & 31;
        const float* src = (n4 < 16) ? w_mu : w_ls;
        float4 v = ((const float4*)src)[k * 16 + (n4 & 15)];
        int gk = k >> 3, kk = k & 7;
        float vv[4] = { v.x, v.y, v.z, v.w };
        #pragma unroll
        for (int j = 0; j < 4; ++j) {
            int nn = n4 * 4 + j;
            int gs = gk ^ (nn & 15);
            Ws[nn * 128 + gs * 8 + kk] = __half_as_ushort(__float2half_rn(vv[j]));
        }
    }
    __syncthreads();

    int wave = tid >> 6, lane = tid & 63;
    int wrow = wave * 32;
    int lr = lane & 15, kg = lane >> 4;
    f32x4 acc[2][8];
    #pragma unroll
    for (int a = 0; a < 2; ++a)
        #pragma unroll
        for (int c = 0; c < 8; ++c)
            acc[a][c] = (f32x4){0.f, 0.f, 0.f, 0.f};

    #pragma unroll
    for (int kc = 0; kc < 4; ++kc) {
        int gbase = kc * 4 + kg;
        int gs = gbase ^ lr;
        s16x8 a0 = *(const s16x8*)(&Hs[(wrow + lr) * 128 + gs * 8]);
        s16x8 a1 = *(const s16x8*)(&Hs[(wrow + 16 + lr) * 128 + gs * 8]);
        #pragma unroll
        for (int c = 0; c < 8; ++c) {
            s16x8 bfr = *(const s16x8*)(&Ws[(c * 16 + lr) * 128 + gs * 8]);
            acc[0][c] = __builtin_amdgcn_mfma_f32_16x16x32_f16(a0, bfr, acc[0][c], 0, 0, 0);
            acc[1][c] = __builtin_amdgcn_mfma_f32_16x16x32_f16(a1, bfr, acc[1][c], 0, 0, 0);
        }
    }

    #pragma unroll
    for (int rf = 0; rf < 2; ++rf)
        #pragma unroll
        for (int j = 0; j < 4; ++j) {
            int gr = row0 + wrow + rf * 16 + kg * 4 + j;
            float muv[4], lsv[4];
            float s2 = 0.f;
            #pragma unroll
            for (int c = 0; c < 4; ++c) {
                muv[c] = acc[rf][c][j] + b_mu[c * 16 + lr];
                float l = acc[rf][4 + c][j] + b_ls[c * 16 + lr];
                lsv[c] = l;
                s2 = fmaf(l, l, s2);
            }
            s2 += __shfl_xor(s2, 1);
            s2 += __shfl_xor(s2, 2);
            s2 += __shfl_xor(s2, 4);
            s2 += __shfl_xor(s2, 8);
            float sc = 1.8f / fmaxf(sqrtf(s2), 1e-12f);
            if (gr < M) {
                size_t base = (size_t)gr * OUT_CH;
                #pragma unroll
                for (int c = 0; c < 4; ++c) {
                    int gc = c * 16 + lr;
                    out[base + gc] = muv[c];
                    out[(size_t)N_NODES * OUT_CH + base + gc] = lsv[c] * sc;
                    out[2 * (size_t)N_NODES * OUT_CH + base + gc] = muv[c];
                }
            }
        }
}

// ---------- host ----------
extern "C" void kernel_launch(void* const* d_in, const int* in_sizes, int n_in,
                              void* d_out, int out_size, void* d_ws, size_t ws_size,
                              hipStream_t stream) {
    const float* x    = (const float*)d_in[0];
    const int*   ei   = (const int*)d_in[1];
    const float* W    = (const float*)d_in[2];
    const float* b    = (const float*)d_in[3];
    const float* w_mu = (const float*)d_in[4];
    const float* b_mu = (const float*)d_in[5];
    const float* w_ls = (const float*)d_in[6];
    const float* b_ls = (const float*)d_in[7];

    const int N = N_NODES, E = N_EDGES;
    const int NB = (N + 255) / 256;
    char* p = (char*)d_ws;
    auto alloc = [&](size_t bytes) {
        char* r = p;
        p += (bytes + 511) & ~(size_t)511;
        return r;
    };
    float*  deg    = (float*)alloc((size_t)N * 4);
    int*    indeg  = (int*)alloc((size_t)N * 4);
    int*    rowptr = (int*)alloc((size_t)(N + 1) * 4);
    int*    cursor = (int*)alloc((size_t)N * 4);
    int*    loc    = (int*)alloc((size_t)N * 4);
    int*    bsum   = (int*)alloc((size_t)(NB + 1) * 4);
    int*    col    = (int*)alloc((size_t)E * 4);
    float*  ew     = (float*)alloc((size_t)E * 4);
    ushort* WT     = (ushort*)alloc((size_t)K_ORD * CH * CH * 2);
    float*  accbuf = (float*)alloc((size_t)N * CH * 4);

    size_t used = (size_t)(p - (char*)d_ws);
    bool bigpath = ws_size >= used + (size_t)K_ORD * SLICE * 2 + (1u << 20);

    hipMemsetAsync(deg, 0, (size_t)N * 4, stream);
    hipMemsetAsync(indeg, 0, (size_t)N * 4, stream);

    count_kernel<<<(E + 255) / 256, 256, 0, stream>>>(ei, deg, indeg, E);
    scan1_kernel<<<NB, 256, 0, stream>>>(indeg, loc, bsum, N);
    scan2_kernel<<<1, 256, 0, stream>>>(bsum, NB);
    scan3_kernel<<<NB, 256, 0, stream>>>(loc, bsum, rowptr, cursor, N, NB);
    scatter_kernel<<<(E + 255) / 256, 256, 0, stream>>>(ei, deg, cursor, col, ew, E);
    wprep_kernel<<<(K_ORD * 128 * 32 + 255) / 256, 256, 0, stream>>>(W, WT);

    int gemm_grid = (N + 127) / 128;
    int prop_grid = (N + 3) / 4;
    int cvt_grid = (N * 16 + 255) / 256;

    if (bigpath) {
        ushort* T = (ushort*)alloc((size_t)K_ORD * SLICE * 2);  // [K][N][128] fp16
        int nn = N;
        void* args[] = { (void*)&x, (void*)&T, (void*)&rowptr,
                         (void*)&col, (void*)&ew, (void*)&nn };
        (void)hipLaunchCooperativeKernel((void*)cheb_kernel, dim3(GRID_C), dim3(256),
                                         args, 0, stream);
        // acc = sum_k T_k @ W_k  (single K=3200 GEMM)
        gemm_kernel<<<gemm_grid, 256, 0, stream>>>(T, SLICE, WT, accbuf, N, 0, K_ORD, 0);
    } else {
        ushort* r0 = (ushort*)alloc(SLICE * 2);
        ushort* r1 = (ushort*)alloc(SLICE * 2);
        ushort* r2 = (ushort*)alloc(SLICE * 2);
        ushort* Ss[3] = { r0, r1, r2 };
        cvt_kernel<<<cvt_grid, 256, 0, stream>>>(x, r0, N * 16);
        gemm_kernel<<<gemm_grid, 256, 0, stream>>>(r0, 0, WT, accbuf, N, 0, 1, 0);
        prop_kernel<<<prop_grid, 256, 0, stream>>>(r0, r0, r1, rowptr, col, ew, N, 0);
        gemm_kernel<<<gemm_grid, 256, 0, stream>>>(r1, 0, WT, accbuf, N, 1, 1, 1);
        for (int k = 2; k < K_ORD; ++k) {
            prop_kernel<<<prop_grid, 256, 0, stream>>>(
                Ss[(k - 1) % 3], Ss[(k - 2) % 3], Ss[k % 3], rowptr, col, ew, N, 1);
            gemm_kernel<<<gemm_grid, 256, 0, stream>>>(Ss[k % 3], 0, WT, accbuf, N, k, 1, 1);
        }
    }

    head_kernel<<<gemm_grid, 256, 0, stream>>>(accbuf, b, w_mu, b_mu, w_ls, b_ls,
                                               (float*)d_out, N);
}